// Round 1
// 2262.442 us; speedup vs baseline: 1.0493x; 1.0493x over previous
//
#include <hip/hip_runtime.h>
#include <hip/hip_bf16.h>

typedef __attribute__((ext_vector_type(8))) short bf16x8;
typedef __attribute__((ext_vector_type(4))) float f32x4;
typedef __hip_bfloat16 bf16;

// ---------------------------------------------------------------------------
// transpose + fp32 -> bf16 convert:  in [batch][R][Cc] -> out [batch][Cc][R]
// ---------------------------------------------------------------------------
__global__ __launch_bounds__(256) void transpose_cvt(
    const float* __restrict__ in, bf16* __restrict__ out, int R, int Cc)
{
  __shared__ float tile[32][33];
  long base = (long)blockIdx.z * R * Cc;
  int c0 = blockIdx.x * 32, r0 = blockIdx.y * 32;
  int tx = threadIdx.x & 31, ty = threadIdx.x >> 5;   // 256 thr: ty 0..7
  #pragma unroll
  for (int i = 0; i < 32; i += 8)
    tile[ty + i][tx] = in[base + (long)(r0 + ty + i) * Cc + (c0 + tx)];
  __syncthreads();
  #pragma unroll
  for (int i = 0; i < 32; i += 8)
    out[base + (long)(c0 + ty + i) * R + (r0 + tx)] =
        __float2bfloat16(tile[tx][ty + i]);
}

// ---------------------------------------------------------------------------
// h = x + pos_emb  (pos broadcast over batch; T*C = 2^20)
// ---------------------------------------------------------------------------
__global__ __launch_bounds__(256) void add_pos(
    const float* __restrict__ x, const float* __restrict__ pos,
    float* __restrict__ h)
{
  int i = blockIdx.x * 1024 + threadIdx.x;
  #pragma unroll
  for (int j = 0; j < 4; ++j) {
    int idx = i + j * 256;
    h[idx] = x[idx] + pos[idx & ((1 << 20) - 1)];
  }
}

__device__ inline float wave_sum(float v) {
  #pragma unroll
  for (int o = 32; o; o >>= 1) v += __shfl_down(v, o, 64);
  return v;
}

// ---------------------------------------------------------------------------
// LayerNorm over rows of 1024; out bf16 (intermediate) or f32 (final)
// ---------------------------------------------------------------------------
template<bool F32OUT>
__global__ __launch_bounds__(256) void layernorm_k(
    const float* __restrict__ x, const float* __restrict__ s,
    const float* __restrict__ b, void* __restrict__ outv)
{
  __shared__ float red[8];
  long row = blockIdx.x;
  const float* xr = x + (row << 10);
  int t = threadIdx.x;
  float v[4]; float sum = 0.f, sq = 0.f;
  #pragma unroll
  for (int i = 0; i < 4; ++i) {
    v[i] = xr[t + i * 256];
    sum += v[i]; sq += v[i] * v[i];
  }
  sum = wave_sum(sum); sq = wave_sum(sq);
  if ((t & 63) == 0) { red[t >> 6] = sum; red[4 + (t >> 6)] = sq; }
  __syncthreads();
  sum = red[0] + red[1] + red[2] + red[3];
  sq  = red[4] + red[5] + red[6] + red[7];
  float mean = sum * (1.f / 1024.f);
  float var  = sq * (1.f / 1024.f) - mean * mean;
  float rstd = rsqrtf(var + 1e-5f);
  #pragma unroll
  for (int i = 0; i < 4; ++i) {
    int c = t + i * 256;
    float y = (v[i] - mean) * rstd * s[c] + b[c];
    if (F32OUT) ((float*)outv)[(row << 10) + c] = y;
    else        ((bf16*)outv)[(row << 10) + c] = __float2bfloat16(y);
  }
}

// ---------------------------------------------------------------------------
// Fused attention: per block = one (b,h) head, one 64-row q stripe.
//   S = q @ k^T   (64 x 1024, K=128)  -- full stripe held in registers
//   P = softmax(S * scale)            -- exact (not online), fp32
//   att out (fp32) written once; P bf16 staged in LDS; o = P @ V via vT.
// 8 waves (512 thr): phase 1 each wave owns a 128-col slice of S;
// phase 2 waves re-tile to (2 m-halves x 4 d-quarters) of the 64x128 o tile.
// q/k/v fragments are read straight from global (L2-resident, 256KB/head).
// ---------------------------------------------------------------------------
__global__ __launch_bounds__(512, 2) void fused_attn(
    const bf16* __restrict__ q, const bf16* __restrict__ kb,
    const bf16* __restrict__ vT, float* __restrict__ attL,
    bf16* __restrict__ o)
{
  __shared__ __align__(16) bf16 p_lds[64 * 1032];   // 64 rows, stride 1032 (pad 8)
  __shared__ float red[2][8][64];
  const int tid  = threadIdx.x;
  const int wave = tid >> 6, lane = tid & 63;
  const int quad = lane >> 4, l16 = lane & 15;
  const int bm = blockIdx.x, bz = blockIdx.y;       // bz = b*8 + h
  const int b = bz >> 3, hh = bz & 7;
  const bf16* qb  = q  + ((long)bz << 17) + ((long)bm << 13);  // 64x128 tile, contiguous
  const bf16* kbz = kb + ((long)bz << 17);
  const bf16* vbz = vT + ((long)bz << 17);
  const int wn = wave << 7;                          // phase-1 col slice

  // ---- phase 1: QK^T, acc[i][j] covers rows i*16.., cols wn + j*16.. ----
  f32x4 acc[4][8] = {};
  #pragma unroll
  for (int kk = 0; kk < 4; ++kk) {
    bf16x8 af[4];
    #pragma unroll
    for (int i = 0; i < 4; ++i)
      af[i] = *(const bf16x8*)(qb + (i * 16 + l16) * 128 + kk * 32 + quad * 8);
    #pragma unroll
    for (int jg = 0; jg < 8; jg += 4) {
      bf16x8 bfr[4];
      #pragma unroll
      for (int j = 0; j < 4; ++j)
        bfr[j] = *(const bf16x8*)(kbz +
            (long)(wn + (jg + j) * 16 + l16) * 128 + kk * 32 + quad * 8);
      #pragma unroll
      for (int j = 0; j < 4; ++j)
        #pragma unroll
        for (int i = 0; i < 4; ++i)
          acc[i][jg + j] = __builtin_amdgcn_mfma_f32_16x16x32_bf16(
              af[i], bfr[j], acc[i][jg + j], 0, 0, 0);
    }
  }

  // ---- softmax: row max (raw scores; scale>0 so max commutes) ----
  float mx[4][4];
  #pragma unroll
  for (int i = 0; i < 4; ++i)
    #pragma unroll
    for (int r = 0; r < 4; ++r) {
      float m = -3.4e38f;
      #pragma unroll
      for (int j = 0; j < 8; ++j) m = fmaxf(m, acc[i][j][r]);
      #pragma unroll
      for (int off = 1; off < 16; off <<= 1) m = fmaxf(m, __shfl_xor(m, off, 64));
      mx[i][r] = m;
    }
  if (l16 == 0) {
    #pragma unroll
    for (int i = 0; i < 4; ++i)
      #pragma unroll
      for (int r = 0; r < 4; ++r)
        red[0][wave][i * 16 + quad * 4 + r] = mx[i][r];
  }
  __syncthreads();
  #pragma unroll
  for (int i = 0; i < 4; ++i)
    #pragma unroll
    for (int r = 0; r < 4; ++r) {
      int row = i * 16 + quad * 4 + r;
      float m = red[0][0][row];
      #pragma unroll
      for (int w = 1; w < 8; ++w) m = fmaxf(m, red[0][w][row]);
      mx[i][r] = m;
    }

  // ---- exp + row sum ----
  const float scale = 0.08838834764831845f;   // 1/sqrt(128)
  float inv[4][4];
  #pragma unroll
  for (int i = 0; i < 4; ++i)
    #pragma unroll
    for (int r = 0; r < 4; ++r) {
      float s = 0.f;
      #pragma unroll
      for (int j = 0; j < 8; ++j) {
        float e = __expf((acc[i][j][r] - mx[i][r]) * scale);
        acc[i][j][r] = e; s += e;
      }
      #pragma unroll
      for (int off = 1; off < 16; off <<= 1) s += __shfl_xor(s, off, 64);
      inv[i][r] = s;
    }
  if (l16 == 0) {
    #pragma unroll
    for (int i = 0; i < 4; ++i)
      #pragma unroll
      for (int r = 0; r < 4; ++r)
        red[1][wave][i * 16 + quad * 4 + r] = inv[i][r];
  }
  __syncthreads();
  #pragma unroll
  for (int i = 0; i < 4; ++i)
    #pragma unroll
    for (int r = 0; r < 4; ++r) {
      int row = i * 16 + quad * 4 + r;
      float s = 0.f;
      #pragma unroll
      for (int w = 0; w < 8; ++w) s += red[1][w][row];
      inv[i][r] = 1.f / s;
    }

  // ---- write att fp32 to out, P bf16 to LDS ----
  long ob = ((long)(hh * 4 + b) << 20) + ((long)(bm * 64) << 10);
  #pragma unroll
  for (int i = 0; i < 4; ++i)
    #pragma unroll
    for (int r = 0; r < 4; ++r) {
      int row = i * 16 + quad * 4 + r;
      float iv = inv[i][r];
      #pragma unroll
      for (int j = 0; j < 8; ++j) {
        float p = acc[i][j][r] * iv;
        int col = wn + j * 16 + l16;
        attL[ob + ((long)row << 10) + col] = p;
        p_lds[row * 1032 + col] = __float2bfloat16(p);
      }
    }
  __syncthreads();

  // ---- phase 2: o = P @ V  (vT is [D][T] so it is the Bt operand) ----
  const int wm2 = (wave >> 2) << 5;   // 0 / 32
  const int wd  = (wave & 3) << 5;    // 0 / 32 / 64 / 96
  f32x4 acc2[2][2] = {};
  #pragma unroll 4
  for (int s0 = 0; s0 < 1024; s0 += 32) {
    bf16x8 pa[2], vv[2];
    #pragma unroll
    for (int i = 0; i < 2; ++i)
      pa[i] = *(const bf16x8*)(p_lds + (wm2 + i * 16 + l16) * 1032 + s0 + quad * 8);
    #pragma unroll
    for (int j = 0; j < 2; ++j)
      vv[j] = *(const bf16x8*)(vbz + (long)(wd + j * 16 + l16) * 1024 + s0 + quad * 8);
    #pragma unroll
    for (int i = 0; i < 2; ++i)
      #pragma unroll
      for (int j = 0; j < 2; ++j)
        acc2[i][j] = __builtin_amdgcn_mfma_f32_16x16x32_bf16(
            pa[i], vv[j], acc2[i][j], 0, 0, 0);
  }
  long ob2 = ((long)b << 20) + ((long)bm << 16) + (hh << 7);
  #pragma unroll
  for (int i = 0; i < 2; ++i)
    #pragma unroll
    for (int j = 0; j < 2; ++j)
      #pragma unroll
      for (int r = 0; r < 4; ++r) {
        int t = wm2 + i * 16 + quad * 4 + r;
        int d = wd + j * 16 + l16;
        o[ob2 + ((long)t << 10) + d] = __float2bfloat16(acc2[i][j][r]);
      }
}

// ---------------------------------------------------------------------------
// Generic bf16 GEMM, C = A[M,K] * Bt[N,K]^T, 128x128 tile, BK=64, 4 waves,
// 4x4 x mfma_f32_16x16x32_bf16 per wave, global_load_lds 16B staging (m97).
// Epilogue variants via template.
// ---------------------------------------------------------------------------
enum { EPI_BHTD = 0, EPI_VT, EPI_SCORES, EPI_ATTV, EPI_RES, EPI_RELU };

template<int EPI>
__global__ __launch_bounds__(256, 2) void gemm_bt(
    const bf16* __restrict__ A, const bf16* __restrict__ Bt,
    void* __restrict__ Cout, const float* __restrict__ bias, float scale,
    int M, int N, int K, int lda, int ldb, long sAb, long sBb)
{
  __shared__ __align__(16) bf16 sA[128 * 64];
  __shared__ __align__(16) bf16 sB[128 * 64];
  const int tid = threadIdx.x;
  const int bn = blockIdx.x, bm = blockIdx.y, bz = blockIdx.z;
  const bf16* Ab = A + bz * sAb + (long)bm * 128 * lda;
  const bf16* Bb = Bt + bz * sBb + (long)bn * 128 * ldb;
  const int wave = tid >> 6, lane = tid & 63;
  const int wm = (wave >> 1) * 64, wn = (wave & 1) * 64;
  const int quad = lane >> 4, l16 = lane & 15;

  f32x4 acc[4][4] = {};

  for (int k0 = 0; k0 < K; k0 += 64) {
    // stage 128x64 bf16 tile = 16 KB = 1024 chunks of 16B -> 4 iters x 256 thr
    #pragma unroll
    for (int i = 0; i < 4; ++i) {
      int c = i * 256 + tid;                 // 16B chunk id, 0..1023
      int row = c >> 3, col = (c & 7) << 3;  // [128 rows][64 cols]
      int ldsoff = (i * 256 + (tid & ~63)) << 3;  // wave-uniform base (elems)
      __builtin_amdgcn_global_load_lds(
          (const __attribute__((address_space(1))) void*)(Ab + (long)row * lda + (k0 + col)),
          (__attribute__((address_space(3))) void*)(sA + ldsoff), 16, 0, 0);
      __builtin_amdgcn_global_load_lds(
          (const __attribute__((address_space(1))) void*)(Bb + (long)row * ldb + (k0 + col)),
          (__attribute__((address_space(3))) void*)(sB + ldsoff), 16, 0, 0);
    }
    __syncthreads();
    #pragma unroll
    for (int kk = 0; kk < 64; kk += 32) {
      bf16x8 af[4], bfr[4];
      #pragma unroll
      for (int i = 0; i < 4; ++i) {
        af[i]  = *(const bf16x8*)(sA + (wm + i * 16 + l16) * 64 + kk + quad * 8);
        bfr[i] = *(const bf16x8*)(sB + (wn + i * 16 + l16) * 64 + kk + quad * 8);
      }
      #pragma unroll
      for (int i = 0; i < 4; ++i)
        #pragma unroll
        for (int j = 0; j < 4; ++j)
          acc[i][j] = __builtin_amdgcn_mfma_f32_16x16x32_bf16(
              af[i], bfr[j], acc[i][j], 0, 0, 0);
    }
    __syncthreads();
  }

  #pragma unroll
  for (int i = 0; i < 4; ++i) {
    #pragma unroll
    for (int j = 0; j < 4; ++j) {
      #pragma unroll
      for (int r = 0; r < 4; ++r) {
        int m = (bm << 7) + wm + i * 16 + (quad << 2) + r;
        int n = (bn << 7) + wn + j * 16 + l16;
        float v = acc[i][j][r];
        if (EPI == EPI_BHTD) {
          // q/k: [B,H,T,D]; m=(b,t), n=(h,d); T*D = 2^17
          long idx = ((long)((m >> 10) * 8 + (n >> 7)) << 17) +
                     ((long)(m & 1023) << 7) + (n & 127);
          ((bf16*)Cout)[idx] = __float2bfloat16(v);
        } else if (EPI == EPI_VT) {
          // vT: [B,H,D,T]
          long idx = ((long)((m >> 10) * 8 + (n >> 7)) << 17) +
                     ((long)(n & 127) << 10) + (m & 1023);
          ((bf16*)Cout)[idx] = __float2bfloat16(v);
        } else if (EPI == EPI_SCORES) {
          // batch bz=(b*8+h); out att layer base, order [h][b][t][s]
          long idx = ((long)((bz & 7) * 4 + (bz >> 3)) << 20) +
                     ((long)m << 10) + n;
          ((float*)Cout)[idx] = v * scale;
        } else if (EPI == EPI_ATTV) {
          // o: [B,T,C]; bz = b*8+h; m=t, n=d
          long idx = ((long)(bz >> 3) << 20) + ((long)m << 10) +
                     ((bz & 7) << 7) + n;
          ((bf16*)Cout)[idx] = __float2bfloat16(v);
        } else if (EPI == EPI_RES) {
          long idx = (long)m * N + n;
          ((float*)Cout)[idx] += v + bias[n];
        } else { // EPI_RELU
          long idx = (long)m * N + n;
          ((bf16*)Cout)[idx] = __float2bfloat16(fmaxf(v + bias[n], 0.f));
        }
      }
    }
  }
}

// ---------------------------------------------------------------------------
extern "C" void kernel_launch(void* const* d_in, const int* in_sizes, int n_in,
                              void* d_out, int out_size, void* d_ws, size_t ws_size,
                              hipStream_t stream)
{
  const float* x     = (const float*)d_in[0];
  const float* pos   = (const float*)d_in[1];
  const float* Wq    = (const float*)d_in[2];
  const float* Wk    = (const float*)d_in[3];
  const float* Wv    = (const float*)d_in[4];
  const float* Wo    = (const float*)d_in[5];
  const float* bo    = (const float*)d_in[6];
  const float* ln1_s = (const float*)d_in[7];
  const float* ln1_b = (const float*)d_in[8];
  const float* ln2_s = (const float*)d_in[9];
  const float* ln2_b = (const float*)d_in[10];
  const float* W1    = (const float*)d_in[11];
  const float* b1    = (const float*)d_in[12];
  const float* W2    = (const float*)d_in[13];
  const float* b2    = (const float*)d_in[14];
  const float* lnf_s = (const float*)d_in[15];
  const float* lnf_b = (const float*)d_in[16];
  float* out = (float*)d_out;

  char* w = (char*)d_ws;
  float* h  = (float*)w;                       // 16 MB  residual stream fp32
  bf16* xn  = (bf16*)(w + (16l  << 20));       //  8 MB  LN output bf16
  bf16* q   = (bf16*)(w + (24l  << 20));       //  8 MB  [B,H,T,D]
  bf16* kb  = (bf16*)(w + (32l  << 20));       //  8 MB  [B,H,T,D]
  bf16* vT  = (bf16*)(w + (40l  << 20));       //  8 MB  [B,H,D,T]
  bf16* o   = (bf16*)(w + (48l  << 20));       //  8 MB  [B,T,C]
  bf16* big = (bf16*)(w + (56l  << 20));       // 64 MB  hbuf (FF1 out)
  bf16* WqT = (bf16*)(w + (120l << 20));       //  8 MB  [L,H*D,C]
  bf16* WkT = (bf16*)(w + (128l << 20));
  bf16* WvT = (bf16*)(w + (136l << 20));
  bf16* WoT = (bf16*)(w + (144l << 20));       //  8 MB  [L,C,C]
  bf16* W1T = (bf16*)(w + (152l << 20));       // 32 MB  [L,F,C]
  bf16* W2T = (bf16*)(w + (184l << 20));       // 32 MB  [L,C,F]  (ends 216MB)

  dim3 blk(256);
  transpose_cvt<<<dim3(4, 32, 32),  blk, 0, stream>>>(Wq, WqT, 1024, 128);
  transpose_cvt<<<dim3(4, 32, 32),  blk, 0, stream>>>(Wk, WkT, 1024, 128);
  transpose_cvt<<<dim3(4, 32, 32),  blk, 0, stream>>>(Wv, WvT, 1024, 128);
  transpose_cvt<<<dim3(32, 32, 4),  blk, 0, stream>>>(Wo, WoT, 1024, 1024);
  transpose_cvt<<<dim3(128, 32, 4), blk, 0, stream>>>(W1, W1T, 1024, 4096);
  transpose_cvt<<<dim3(32, 128, 4), blk, 0, stream>>>(W2, W2T, 4096, 1024);

  add_pos<<<4096, blk, 0, stream>>>(x, pos, h);

  for (int l = 0; l < 4; ++l) {
    layernorm_k<false><<<4096, blk, 0, stream>>>(h, ln1_s + l * 1024, ln1_b + l * 1024, xn);
    gemm_bt<EPI_BHTD><<<dim3(8, 32, 1), blk, 0, stream>>>(
        xn, WqT + (long)l * 1048576, q, nullptr, 0.f, 4096, 1024, 1024, 1024, 1024, 0, 0);
    gemm_bt<EPI_BHTD><<<dim3(8, 32, 1), blk, 0, stream>>>(
        xn, WkT + (long)l * 1048576, kb, nullptr, 0.f, 4096, 1024, 1024, 1024, 1024, 0, 0);
    gemm_bt<EPI_VT><<<dim3(8, 32, 1), blk, 0, stream>>>(
        xn, WvT + (long)l * 1048576, vT, nullptr, 0.f, 4096, 1024, 1024, 1024, 1024, 0, 0);

    float* attL = out + 4194304l + (long)l * 33554432l;  // atts[l] base
    fused_attn<<<dim3(16, 32), dim3(512), 0, stream>>>(q, kb, vT, attL, o);

    gemm_bt<EPI_RES><<<dim3(8, 32, 1), blk, 0, stream>>>(
        o, WoT + (long)l * 1048576, h, bo + l * 1024, 0.f, 4096, 1024, 1024, 1024, 1024, 0, 0);

    layernorm_k<false><<<4096, blk, 0, stream>>>(h, ln2_s + l * 1024, ln2_b + l * 1024, xn);
    gemm_bt<EPI_RELU><<<dim3(32, 32, 1), blk, 0, stream>>>(
        xn, W1T + (long)l * 4194304, big, b1 + l * 4096, 0.f, 4096, 4096, 1024, 1024, 1024, 0, 0);
    gemm_bt<EPI_RES><<<dim3(8, 32, 1), blk, 0, stream>>>(
        big, W2T + (long)l * 4194304, h, b2 + l * 1024, 0.f, 4096, 1024, 4096, 4096, 4096, 0, 0);
  }
  layernorm_k<true><<<4096, blk, 0, stream>>>(h, lnf_s, lnf_b, out);
}

// Round 2
// 1970.292 us; speedup vs baseline: 1.2049x; 1.1483x over previous
//
#include <hip/hip_runtime.h>
#include <hip/hip_bf16.h>

typedef __attribute__((ext_vector_type(8))) short bf16x8;
typedef __attribute__((ext_vector_type(4))) float f32x4;
typedef __hip_bfloat16 bf16;

// ---------------------------------------------------------------------------
// transpose + fp32 -> bf16 convert:  in [batch][R][Cc] -> out [batch][Cc][R]
// ---------------------------------------------------------------------------
__global__ __launch_bounds__(256) void transpose_cvt(
    const float* __restrict__ in, bf16* __restrict__ out, int R, int Cc)
{
  __shared__ float tile[32][33];
  long base = (long)blockIdx.z * R * Cc;
  int c0 = blockIdx.x * 32, r0 = blockIdx.y * 32;
  int tx = threadIdx.x & 31, ty = threadIdx.x >> 5;   // 256 thr: ty 0..7
  #pragma unroll
  for (int i = 0; i < 32; i += 8)
    tile[ty + i][tx] = in[base + (long)(r0 + ty + i) * Cc + (c0 + tx)];
  __syncthreads();
  #pragma unroll
  for (int i = 0; i < 32; i += 8)
    out[base + (long)(c0 + ty + i) * R + (r0 + tx)] =
        __float2bfloat16(tile[tx][ty + i]);
}

// ---------------------------------------------------------------------------
// h = x + pos_emb  (pos broadcast over batch; T*C = 2^20)
// ---------------------------------------------------------------------------
__global__ __launch_bounds__(256) void add_pos(
    const float* __restrict__ x, const float* __restrict__ pos,
    float* __restrict__ h)
{
  int i = blockIdx.x * 1024 + threadIdx.x;
  #pragma unroll
  for (int j = 0; j < 4; ++j) {
    int idx = i + j * 256;
    h[idx] = x[idx] + pos[idx & ((1 << 20) - 1)];
  }
}

__device__ inline float wave_sum(float v) {
  #pragma unroll
  for (int o = 32; o; o >>= 1) v += __shfl_down(v, o, 64);
  return v;
}

// ---------------------------------------------------------------------------
// LayerNorm over rows of 1024; out bf16 (intermediate) or f32 (final)
// ---------------------------------------------------------------------------
template<bool F32OUT>
__global__ __launch_bounds__(256) void layernorm_k(
    const float* __restrict__ x, const float* __restrict__ s,
    const float* __restrict__ b, void* __restrict__ outv)
{
  __shared__ float red[8];
  long row = blockIdx.x;
  const float* xr = x + (row << 10);
  int t = threadIdx.x;
  float v[4]; float sum = 0.f, sq = 0.f;
  #pragma unroll
  for (int i = 0; i < 4; ++i) {
    v[i] = xr[t + i * 256];
    sum += v[i]; sq += v[i] * v[i];
  }
  sum = wave_sum(sum); sq = wave_sum(sq);
  if ((t & 63) == 0) { red[t >> 6] = sum; red[4 + (t >> 6)] = sq; }
  __syncthreads();
  sum = red[0] + red[1] + red[2] + red[3];
  sq  = red[4] + red[5] + red[6] + red[7];
  float mean = sum * (1.f / 1024.f);
  float var  = sq * (1.f / 1024.f) - mean * mean;
  float rstd = rsqrtf(var + 1e-5f);
  #pragma unroll
  for (int i = 0; i < 4; ++i) {
    int c = t + i * 256;
    float y = (v[i] - mean) * rstd * s[c] + b[c];
    if (F32OUT) ((float*)outv)[(row << 10) + c] = y;
    else        ((bf16*)outv)[(row << 10) + c] = __float2bfloat16(y);
  }
}

// ---------------------------------------------------------------------------
// Fused attention: per block = one (b,h) head, one 64-row q stripe.
//   S = q @ k^T   (64 x 1024, K=128)  -- full stripe held in registers
//   P = softmax(S * scale)            -- exact (not online), fp32
//   att out (fp32) written once; P bf16 staged in LDS; o = P @ V via vT.
// ---------------------------------------------------------------------------
__global__ __launch_bounds__(512, 2) void fused_attn(
    const bf16* __restrict__ q, const bf16* __restrict__ kb,
    const bf16* __restrict__ vT, float* __restrict__ attL,
    bf16* __restrict__ o)
{
  __shared__ __align__(16) bf16 p_lds[64 * 1032];   // 64 rows, stride 1032 (pad 8)
  __shared__ float red[2][8][64];
  const int tid  = threadIdx.x;
  const int wave = tid >> 6, lane = tid & 63;
  const int quad = lane >> 4, l16 = lane & 15;
  const int bm = blockIdx.x, bz = blockIdx.y;       // bz = b*8 + h
  const int b = bz >> 3, hh = bz & 7;
  const bf16* qb  = q  + ((long)bz << 17) + ((long)bm << 13);  // 64x128 tile, contiguous
  const bf16* kbz = kb + ((long)bz << 17);
  const bf16* vbz = vT + ((long)bz << 17);
  const int wn = wave << 7;                          // phase-1 col slice

  // ---- phase 1: QK^T, acc[i][j] covers rows i*16.., cols wn + j*16.. ----
  f32x4 acc[4][8] = {};
  #pragma unroll
  for (int kk = 0; kk < 4; ++kk) {
    bf16x8 af[4];
    #pragma unroll
    for (int i = 0; i < 4; ++i)
      af[i] = *(const bf16x8*)(qb + (i * 16 + l16) * 128 + kk * 32 + quad * 8);
    #pragma unroll
    for (int jg = 0; jg < 8; jg += 4) {
      bf16x8 bfr[4];
      #pragma unroll
      for (int j = 0; j < 4; ++j)
        bfr[j] = *(const bf16x8*)(kbz +
            (long)(wn + (jg + j) * 16 + l16) * 128 + kk * 32 + quad * 8);
      #pragma unroll
      for (int j = 0; j < 4; ++j)
        #pragma unroll
        for (int i = 0; i < 4; ++i)
          acc[i][jg + j] = __builtin_amdgcn_mfma_f32_16x16x32_bf16(
              af[i], bfr[j], acc[i][jg + j], 0, 0, 0);
    }
  }

  // ---- softmax: row max (raw scores; scale>0 so max commutes) ----
  float mx[4][4];
  #pragma unroll
  for (int i = 0; i < 4; ++i)
    #pragma unroll
    for (int r = 0; r < 4; ++r) {
      float m = -3.4e38f;
      #pragma unroll
      for (int j = 0; j < 8; ++j) m = fmaxf(m, acc[i][j][r]);
      #pragma unroll
      for (int off = 1; off < 16; off <<= 1) m = fmaxf(m, __shfl_xor(m, off, 64));
      mx[i][r] = m;
    }
  if (l16 == 0) {
    #pragma unroll
    for (int i = 0; i < 4; ++i)
      #pragma unroll
      for (int r = 0; r < 4; ++r)
        red[0][wave][i * 16 + quad * 4 + r] = mx[i][r];
  }
  __syncthreads();
  #pragma unroll
  for (int i = 0; i < 4; ++i)
    #pragma unroll
    for (int r = 0; r < 4; ++r) {
      int row = i * 16 + quad * 4 + r;
      float m = red[0][0][row];
      #pragma unroll
      for (int w = 1; w < 8; ++w) m = fmaxf(m, red[0][w][row]);
      mx[i][r] = m;
    }

  // ---- exp + row sum ----
  const float scale = 0.08838834764831845f;   // 1/sqrt(128)
  float inv[4][4];
  #pragma unroll
  for (int i = 0; i < 4; ++i)
    #pragma unroll
    for (int r = 0; r < 4; ++r) {
      float s = 0.f;
      #pragma unroll
      for (int j = 0; j < 8; ++j) {
        float e = __expf((acc[i][j][r] - mx[i][r]) * scale);
        acc[i][j][r] = e; s += e;
      }
      #pragma unroll
      for (int off = 1; off < 16; off <<= 1) s += __shfl_xor(s, off, 64);
      inv[i][r] = s;
    }
  if (l16 == 0) {
    #pragma unroll
    for (int i = 0; i < 4; ++i)
      #pragma unroll
      for (int r = 0; r < 4; ++r)
        red[1][wave][i * 16 + quad * 4 + r] = inv[i][r];
  }
  __syncthreads();
  #pragma unroll
  for (int i = 0; i < 4; ++i)
    #pragma unroll
    for (int r = 0; r < 4; ++r) {
      int row = i * 16 + quad * 4 + r;
      float s = 0.f;
      #pragma unroll
      for (int w = 0; w < 8; ++w) s += red[1][w][row];
      inv[i][r] = 1.f / s;
    }

  // ---- write att fp32 to out, P bf16 to LDS ----
  long ob = ((long)(hh * 4 + b) << 20) + ((long)(bm * 64) << 10);
  #pragma unroll
  for (int i = 0; i < 4; ++i)
    #pragma unroll
    for (int r = 0; r < 4; ++r) {
      int row = i * 16 + quad * 4 + r;
      float iv = inv[i][r];
      #pragma unroll
      for (int j = 0; j < 8; ++j) {
        float p = acc[i][j][r] * iv;
        int col = wn + j * 16 + l16;
        attL[ob + ((long)row << 10) + col] = p;
        p_lds[row * 1032 + col] = __float2bfloat16(p);
      }
    }
  __syncthreads();

  // ---- phase 2: o = P @ V  (vT is [D][T] so it is the Bt operand) ----
  const int wm2 = (wave >> 2) << 5;   // 0 / 32
  const int wd  = (wave & 3) << 5;    // 0 / 32 / 64 / 96
  f32x4 acc2[2][2] = {};
  #pragma unroll 4
  for (int s0 = 0; s0 < 1024; s0 += 32) {
    bf16x8 pa[2], vv[2];
    #pragma unroll
    for (int i = 0; i < 2; ++i)
      pa[i] = *(const bf16x8*)(p_lds + (wm2 + i * 16 + l16) * 1032 + s0 + quad * 8);
    #pragma unroll
    for (int j = 0; j < 2; ++j)
      vv[j] = *(const bf16x8*)(vbz + (long)(wd + j * 16 + l16) * 1024 + s0 + quad * 8);
    #pragma unroll
    for (int i = 0; i < 2; ++i)
      #pragma unroll
      for (int j = 0; j < 2; ++j)
        acc2[i][j] = __builtin_amdgcn_mfma_f32_16x16x32_bf16(
            pa[i], vv[j], acc2[i][j], 0, 0, 0);
  }
  long ob2 = ((long)b << 20) + ((long)bm << 16) + (hh << 7);
  #pragma unroll
  for (int i = 0; i < 2; ++i)
    #pragma unroll
    for (int j = 0; j < 2; ++j)
      #pragma unroll
      for (int r = 0; r < 4; ++r) {
        int t = wm2 + i * 16 + quad * 4 + r;
        int d = wd + j * 16 + l16;
        o[ob2 + ((long)t << 10) + d] = __float2bfloat16(acc2[i][j][r]);
      }
}

// ---------------------------------------------------------------------------
// Generic bf16 GEMM, C = A[M,K] * Bt[N,K]^T, 128x128 tile, BK=64, 4 waves,
// 4x4 x mfma_f32_16x16x32_bf16 per wave, global_load_lds 16B staging (m97).
// Epilogue variants via template.
//   EPI_QKV:    grid.z in {0,1,2} selects Wq/Wk/Wv (sBb = weight stride) and
//               writes q / kb (BHTD) or vT (B,H,D,T); outputs contiguous 4M.
//   EPI_RES_AT: split-K via grid.z (sAb/sBb = K column offset); atomicAdd
//               into fp32 residual, bias added by z==0 only.
// ---------------------------------------------------------------------------
enum { EPI_BHTD = 0, EPI_VT, EPI_QKV, EPI_RES, EPI_RES_AT, EPI_RELU };

template<int EPI>
__global__ __launch_bounds__(256, 2) void gemm_bt(
    const bf16* __restrict__ A, const bf16* __restrict__ Bt,
    void* __restrict__ Cout, const float* __restrict__ bias, float scale,
    int M, int N, int K, int lda, int ldb, long sAb, long sBb)
{
  __shared__ __align__(16) bf16 sA[128 * 64];
  __shared__ __align__(16) bf16 sB[128 * 64];
  const int tid = threadIdx.x;
  const int bn = blockIdx.x, bm = blockIdx.y, bz = blockIdx.z;
  const bf16* Ab = A + bz * sAb + (long)bm * 128 * lda;
  const bf16* Bb = Bt + bz * sBb + (long)bn * 128 * ldb;
  const int wave = tid >> 6, lane = tid & 63;
  const int wm = (wave >> 1) * 64, wn = (wave & 1) * 64;
  const int quad = lane >> 4, l16 = lane & 15;

  f32x4 acc[4][4] = {};

  for (int k0 = 0; k0 < K; k0 += 64) {
    // stage 128x64 bf16 tile = 16 KB = 1024 chunks of 16B -> 4 iters x 256 thr
    #pragma unroll
    for (int i = 0; i < 4; ++i) {
      int c = i * 256 + tid;                 // 16B chunk id, 0..1023
      int row = c >> 3, col = (c & 7) << 3;  // [128 rows][64 cols]
      int ldsoff = (i * 256 + (tid & ~63)) << 3;  // wave-uniform base (elems)
      __builtin_amdgcn_global_load_lds(
          (const __attribute__((address_space(1))) void*)(Ab + (long)row * lda + (k0 + col)),
          (__attribute__((address_space(3))) void*)(sA + ldsoff), 16, 0, 0);
      __builtin_amdgcn_global_load_lds(
          (const __attribute__((address_space(1))) void*)(Bb + (long)row * ldb + (k0 + col)),
          (__attribute__((address_space(3))) void*)(sB + ldsoff), 16, 0, 0);
    }
    __syncthreads();
    #pragma unroll
    for (int kk = 0; kk < 64; kk += 32) {
      bf16x8 af[4], bfr[4];
      #pragma unroll
      for (int i = 0; i < 4; ++i) {
        af[i]  = *(const bf16x8*)(sA + (wm + i * 16 + l16) * 64 + kk + quad * 8);
        bfr[i] = *(const bf16x8*)(sB + (wn + i * 16 + l16) * 64 + kk + quad * 8);
      }
      #pragma unroll
      for (int i = 0; i < 4; ++i)
        #pragma unroll
        for (int j = 0; j < 4; ++j)
          acc[i][j] = __builtin_amdgcn_mfma_f32_16x16x32_bf16(
              af[i], bfr[j], acc[i][j], 0, 0, 0);
    }
    __syncthreads();
  }

  #pragma unroll
  for (int i = 0; i < 4; ++i) {
    #pragma unroll
    for (int j = 0; j < 4; ++j) {
      #pragma unroll
      for (int r = 0; r < 4; ++r) {
        int m = (bm << 7) + wm + i * 16 + (quad << 2) + r;
        int n = (bn << 7) + wn + j * 16 + l16;
        float v = acc[i][j][r];
        if (EPI == EPI_BHTD) {
          // q/k: [B,H,T,D]; m=(b,t), n=(h,d); T*D = 2^17
          long idx = ((long)((m >> 10) * 8 + (n >> 7)) << 17) +
                     ((long)(m & 1023) << 7) + (n & 127);
          ((bf16*)Cout)[idx] = __float2bfloat16(v);
        } else if (EPI == EPI_VT) {
          // vT: [B,H,D,T]
          long idx = ((long)((m >> 10) * 8 + (n >> 7)) << 17) +
                     ((long)(n & 127) << 10) + (m & 1023);
          ((bf16*)Cout)[idx] = __float2bfloat16(v);
        } else if (EPI == EPI_QKV) {
          // z=0 -> q [B,H,T,D], z=1 -> kb [B,H,T,D], z=2 -> vT [B,H,D,T]
          bf16* dst = (bf16*)Cout + (long)bz * 4194304;
          long idx;
          if (bz < 2)
            idx = ((long)((m >> 10) * 8 + (n >> 7)) << 17) +
                  ((long)(m & 1023) << 7) + (n & 127);
          else
            idx = ((long)((m >> 10) * 8 + (n >> 7)) << 17) +
                  ((long)(n & 127) << 10) + (m & 1023);
          dst[idx] = __float2bfloat16(v);
        } else if (EPI == EPI_RES) {
          long idx = (long)m * N + n;
          ((float*)Cout)[idx] += v + bias[n];
        } else if (EPI == EPI_RES_AT) {
          long idx = (long)m * N + n;
          atomicAdd(&((float*)Cout)[idx], v + (bz == 0 ? bias[n] : 0.f));
        } else { // EPI_RELU
          long idx = (long)m * N + n;
          ((bf16*)Cout)[idx] = __float2bfloat16(fmaxf(v + bias[n], 0.f));
        }
      }
    }
  }
}

// ---------------------------------------------------------------------------
extern "C" void kernel_launch(void* const* d_in, const int* in_sizes, int n_in,
                              void* d_out, int out_size, void* d_ws, size_t ws_size,
                              hipStream_t stream)
{
  const float* x     = (const float*)d_in[0];
  const float* pos   = (const float*)d_in[1];
  const float* Wq    = (const float*)d_in[2];
  const float* Wk    = (const float*)d_in[3];
  const float* Wv    = (const float*)d_in[4];
  const float* Wo    = (const float*)d_in[5];
  const float* bo    = (const float*)d_in[6];
  const float* ln1_s = (const float*)d_in[7];
  const float* ln1_b = (const float*)d_in[8];
  const float* ln2_s = (const float*)d_in[9];
  const float* ln2_b = (const float*)d_in[10];
  const float* W1    = (const float*)d_in[11];
  const float* b1    = (const float*)d_in[12];
  const float* W2    = (const float*)d_in[13];
  const float* b2    = (const float*)d_in[14];
  const float* lnf_s = (const float*)d_in[15];
  const float* lnf_b = (const float*)d_in[16];
  float* out = (float*)d_out;

  char* w = (char*)d_ws;
  float* h  = (float*)w;                       // 16 MB  residual stream fp32
  bf16* xn  = (bf16*)(w + (16l  << 20));       //  8 MB  LN output bf16
  bf16* q   = (bf16*)(w + (24l  << 20));       //  8 MB  [B,H,T,D]
  bf16* kb  = (bf16*)(w + (32l  << 20));       //  8 MB  [B,H,T,D]   (q+4M)
  bf16* vT  = (bf16*)(w + (40l  << 20));       //  8 MB  [B,H,D,T]   (q+8M)
  bf16* o   = (bf16*)(w + (48l  << 20));       //  8 MB  [B,T,C]
  bf16* big = (bf16*)(w + (56l  << 20));       // 64 MB  hbuf (FF1 out)
  bf16* WqT = (bf16*)(w + (120l << 20));       //  8 MB  [L,H*D,C]
  bf16* WkT = (bf16*)(w + (128l << 20));       //        (WqT+4M)
  bf16* WvT = (bf16*)(w + (136l << 20));       //        (WqT+8M)
  bf16* WoT = (bf16*)(w + (144l << 20));       //  8 MB  [L,C,C]
  bf16* W1T = (bf16*)(w + (152l << 20));       // 32 MB  [L,F,C]
  bf16* W2T = (bf16*)(w + (184l << 20));       // 32 MB  [L,C,F]  (ends 216MB)

  dim3 blk(256);
  transpose_cvt<<<dim3(4, 32, 32),  blk, 0, stream>>>(Wq, WqT, 1024, 128);
  transpose_cvt<<<dim3(4, 32, 32),  blk, 0, stream>>>(Wk, WkT, 1024, 128);
  transpose_cvt<<<dim3(4, 32, 32),  blk, 0, stream>>>(Wv, WvT, 1024, 128);
  transpose_cvt<<<dim3(32, 32, 4),  blk, 0, stream>>>(Wo, WoT, 1024, 1024);
  transpose_cvt<<<dim3(128, 32, 4), blk, 0, stream>>>(W1, W1T, 1024, 4096);
  transpose_cvt<<<dim3(32, 128, 4), blk, 0, stream>>>(W2, W2T, 4096, 1024);

  add_pos<<<4096, blk, 0, stream>>>(x, pos, h);

  for (int l = 0; l < 4; ++l) {
    layernorm_k<false><<<4096, blk, 0, stream>>>(h, ln1_s + l * 1024, ln1_b + l * 1024, xn);
    // merged QKV: z selects weight (stride 4M elems) and output (stride 4M elems)
    gemm_bt<EPI_QKV><<<dim3(8, 32, 3), blk, 0, stream>>>(
        xn, WqT + (long)l * 1048576, q, nullptr, 0.f,
        4096, 1024, 1024, 1024, 1024, 0, 4194304l);

    float* attL = out + 4194304l + (long)l * 33554432l;  // atts[l] base
    fused_attn<<<dim3(16, 32), dim3(512), 0, stream>>>(q, kb, vT, attL, o);

    // proj: split-K=2 (z advances A/B by 512 cols), atomic accumulate into h
    gemm_bt<EPI_RES_AT><<<dim3(8, 32, 2), blk, 0, stream>>>(
        o, WoT + (long)l * 1048576, h, bo + l * 1024, 0.f,
        4096, 1024, 512, 1024, 1024, 512, 512);

    layernorm_k<false><<<4096, blk, 0, stream>>>(h, ln2_s + l * 1024, ln2_b + l * 1024, xn);
    gemm_bt<EPI_RELU><<<dim3(32, 32, 1), blk, 0, stream>>>(
        xn, W1T + (long)l * 4194304, big, b1 + l * 4096, 0.f,
        4096, 4096, 1024, 1024, 1024, 0, 0);
    // FF2: split-K=2 (z advances A/B by 2048 cols), atomic accumulate into h
    gemm_bt<EPI_RES_AT><<<dim3(8, 32, 2), blk, 0, stream>>>(
        big, W2T + (long)l * 4194304, h, b2 + l * 1024, 0.f,
        4096, 1024, 2048, 4096, 4096, 2048, 2048);
  }
  layernorm_k<true><<<4096, blk, 0, stream>>>(h, lnf_s, lnf_b, out);
}